// Round 4
// baseline (466.564 us; speedup 1.0000x reference)
//
#include <hip/hip_runtime.h>
#include <hip/hip_bf16.h>

#define NN 8192
#define DIN 128
#define DOUT 128

typedef __bf16 bf16;
typedef __bf16 bf16x8 __attribute__((ext_vector_type(8)));
typedef float f32x4 __attribute__((ext_vector_type(4)));

// ---- K1: rowsum -> dinv[i] = rsqrt(sum(adj[i,:]) + eps). Pure stream. ----
__global__ __launch_bounds__(256) void k1_rowsum(const float* __restrict__ adj,
                                                 float* __restrict__ dinv) {
    int row = blockIdx.x;
    int t   = threadIdx.x;
    const float4* p = reinterpret_cast<const float4*>(adj + (size_t)row * NN);
    float s = 0.f;
    #pragma unroll
    for (int i = 0; i < 8; ++i) {
        float4 v = p[t + i * 256];
        s += (v.x + v.y) + (v.z + v.w);
    }
    #pragma unroll
    for (int off = 32; off > 0; off >>= 1) s += __shfl_down(s, off, 64);
    __shared__ float r4[4];
    if ((t & 63) == 0) r4[t >> 6] = s;
    __syncthreads();
    if (t == 0) dinv[row] = rsqrtf(((r4[0] + r4[1]) + (r4[2] + r4[3])) + 1e-6f);
}

// ---- K2: z = x @ W^T;  yT[c][j] = bf16(dinv[j] * z[j][c])  (transposed) --
__global__ __launch_bounds__(256) void k2_xwT(const float* __restrict__ x,
                                              const float* __restrict__ W,
                                              const float* __restrict__ dinv,
                                              bf16* __restrict__ yT) {
    __shared__ float Wl[128 * 132];
    __shared__ float xl[32 * 132];
    __shared__ float dl[32];
    int t  = threadIdx.x;
    int i0 = blockIdx.x * 32;
    if (t < 32) dl[t] = dinv[i0 + t];
    #pragma unroll
    for (int s = 0; s < 16; ++s) {
        int i  = t + s * 256;
        int o  = i >> 5;
        int c4 = i & 31;
        *reinterpret_cast<float4*>(&Wl[o * 132 + c4 * 4]) =
            *reinterpret_cast<const float4*>(W + o * 128 + c4 * 4);
    }
    #pragma unroll
    for (int s = 0; s < 4; ++s) {
        int i   = t + s * 256;
        int row = i >> 5;
        int c4  = i & 31;
        *reinterpret_cast<float4*>(&xl[row * 132 + c4 * 4]) =
            *reinterpret_cast<const float4*>(x + (size_t)(i0 + row) * DIN + c4 * 4);
    }
    __syncthreads();
    int o = t & 127;
    int g = t >> 7;
    float acc[16] = {};
    for (int c4 = 0; c4 < 32; ++c4) {
        float4 w4 = *reinterpret_cast<const float4*>(&Wl[o * 132 + c4 * 4]);
        #pragma unroll
        for (int r = 0; r < 16; ++r) {
            float4 h4 = *reinterpret_cast<const float4*>(&xl[(g * 16 + r) * 132 + c4 * 4]);
            acc[r] += h4.x * w4.x + h4.y * w4.y + h4.z * w4.z + h4.w * w4.w;
        }
    }
    bf16x8 o0, o1;
    #pragma unroll
    for (int r = 0; r < 8; ++r) o0[r] = (bf16)(acc[r] * dl[g * 16 + r]);
    #pragma unroll
    for (int r = 0; r < 8; ++r) o1[r] = (bf16)(acc[8 + r] * dl[g * 16 + 8 + r]);
    bf16* dst = yT + (size_t)o * NN + i0 + g * 16;
    *reinterpret_cast<bf16x8*>(dst)     = o0;
    *reinterpret_cast<bf16x8*>(dst + 8) = o1;
}

// ---- K0: out[i][c] = bias[c]  (atomic accumulation target) ---------------
__global__ __launch_bounds__(256) void k0_init(const float* __restrict__ bias,
                                               float* __restrict__ out) {
    int g = blockIdx.x * 256 + threadIdx.x;
    float4 b4 = *reinterpret_cast<const float4*>(bias + (threadIdx.x & 31) * 4);
    *reinterpret_cast<float4*>(out + (size_t)g * 4) = b4;
}

// ---- K3: out += dinv[i] * (adj[i, ksplit] @ y[ksplit, :]) ----------------
// B-slice resident in LDS (one barrier). A streamed fp32 from global with an
// explicit 2-kstep register double-buffer: loads for batch n+1 issue before
// batch n's 32 MFMAs, so vmcnt-granular waits overlap HBM latency.
#define KR 512
#define LDB3 520   // 1040 B row stride: 16B-aligned, conflict-free b128

__global__ __launch_bounds__(512, 2) void k3_spmm(const float* __restrict__ adj,
                                                  const bf16* __restrict__ yT,
                                                  const float* __restrict__ dinv,
                                                  float* __restrict__ out) {
    __shared__ bf16 BL[128 * LDB3];   // 130 KB -> 1 block/CU, 8 waves
    int t     = threadIdx.x;
    int split = blockIdx.x & 15;
    int mg    = blockIdx.x >> 4;
    int m0    = mg * 256;
    int k0    = split * KR;
    for (int i = t; i < 128 * 64; i += 512) {
        int c = i >> 6, ch = i & 63;
        *reinterpret_cast<uint4*>(&BL[c * LDB3 + ch * 8]) =
            *reinterpret_cast<const uint4*>(yT + (size_t)c * NN + k0 + ch * 8);
    }
    __syncthreads();                  // the only barrier

    int wave = t >> 6, lane = t & 63;
    int mrow = lane & 15, quad = lane >> 4;
    int wm0  = wave * 32 + m0;

    f32x4 dv0 = *reinterpret_cast<const f32x4*>(dinv + wm0 + quad * 4);
    f32x4 dv1 = *reinterpret_cast<const f32x4*>(dinv + wm0 + 16 + quad * 4);

    f32x4 acc[2][8] = {};
    const float* a0p = adj + (size_t)(wm0 + mrow) * NN + k0 + quad * 8;
    const float* a1p = a0p + (size_t)16 * NN;

    // register double-buffer: [strip][kstep-in-batch][half-float4]
    float4 cur[2][2][2], nxt[2][2][2];
    #pragma unroll
    for (int ks = 0; ks < 2; ++ks) {
        cur[0][ks][0] = *(const float4*)(a0p + ks * 32);
        cur[0][ks][1] = *(const float4*)(a0p + ks * 32 + 4);
        cur[1][ks][0] = *(const float4*)(a1p + ks * 32);
        cur[1][ks][1] = *(const float4*)(a1p + ks * 32 + 4);
    }
    #pragma unroll
    for (int b = 0; b < KR / 64; ++b) {          // 8 batches of 2 ksteps
        if (b < KR / 64 - 1) {
            const float* p0 = a0p + (b + 1) * 64;
            const float* p1 = a1p + (b + 1) * 64;
            #pragma unroll
            for (int ks = 0; ks < 2; ++ks) {
                nxt[0][ks][0] = *(const float4*)(p0 + ks * 32);
                nxt[0][ks][1] = *(const float4*)(p0 + ks * 32 + 4);
                nxt[1][ks][0] = *(const float4*)(p1 + ks * 32);
                nxt[1][ks][1] = *(const float4*)(p1 + ks * 32 + 4);
            }
        }
        #pragma unroll
        for (int ks = 0; ks < 2; ++ks) {
            int boff = (b * 2 + ks) * 32 + quad * 8;
            bf16x8 bf[8];
            #pragma unroll
            for (int nt = 0; nt < 8; ++nt)
                bf[nt] = *reinterpret_cast<const bf16x8*>(&BL[(nt * 16 + mrow) * LDB3 + boff]);
            float4 A0 = cur[0][ks][0], A0b = cur[0][ks][1];
            float4 A1 = cur[1][ks][0], A1b = cur[1][ks][1];
            bf16x8 af0 = { (bf16)A0.x, (bf16)A0.y, (bf16)A0.z, (bf16)A0.w,
                           (bf16)A0b.x, (bf16)A0b.y, (bf16)A0b.z, (bf16)A0b.w };
            bf16x8 af1 = { (bf16)A1.x, (bf16)A1.y, (bf16)A1.z, (bf16)A1.w,
                           (bf16)A1b.x, (bf16)A1b.y, (bf16)A1b.z, (bf16)A1b.w };
            #pragma unroll
            for (int nt = 0; nt < 8; ++nt) {
                acc[0][nt] = __builtin_amdgcn_mfma_f32_16x16x32_bf16(af0, bf[nt], acc[0][nt], 0, 0, 0);
                acc[1][nt] = __builtin_amdgcn_mfma_f32_16x16x32_bf16(af1, bf[nt], acc[1][nt], 0, 0, 0);
            }
        }
        if (b < KR / 64 - 1) {
            #pragma unroll
            for (int st = 0; st < 2; ++st)
                #pragma unroll
                for (int ks = 0; ks < 2; ++ks) {
                    cur[st][ks][0] = nxt[st][ks][0];
                    cur[st][ks][1] = nxt[st][ks][1];
                }
        }
    }
    // epilogue: D[row=quad*4+r][col=lane&15]; scale by dinv[row], atomic-add
    #pragma unroll
    for (int nt = 0; nt < 8; ++nt) {
        int col = nt * 16 + mrow;
        #pragma unroll
        for (int r = 0; r < 4; ++r) {
            unsafeAtomicAdd(out + (size_t)(wm0 + quad * 4 + r) * DOUT + col,
                            acc[0][nt][r] * dv0[r]);
            unsafeAtomicAdd(out + (size_t)(wm0 + 16 + quad * 4 + r) * DOUT + col,
                            acc[1][nt][r] * dv1[r]);
        }
    }
}

extern "C" void kernel_launch(void* const* d_in, const int* in_sizes, int n_in,
                              void* d_out, int out_size, void* d_ws, size_t ws_size,
                              hipStream_t stream) {
    const float* x   = (const float*)d_in[0];
    const float* adj = (const float*)d_in[1];
    const float* W   = (const float*)d_in[2];
    const float* b   = (const float*)d_in[3];
    float* out = (float*)d_out;
    char* ws = (char*)d_ws;
    float* dinv = (float*)ws;                   // 32 KB  @ 0
    bf16*  yT   = (bf16*)(ws + (1u << 20));     // 2 MB   @ 1 MB

    k1_rowsum<<<NN, 256, 0, stream>>>(adj, dinv);
    k2_xwT   <<<NN / 32, 256, 0, stream>>>(x, W, dinv, yT);
    k0_init  <<<(NN * DOUT / 4) / 256, 256, 0, stream>>>(b, out);
    k3_spmm  <<<16 * (NN / 256), 512, 0, stream>>>(adj, yT, dinv, out);
}